// Round 1
// baseline (135.282 us; speedup 1.0000x reference)
//
#include <hip/hip_runtime.h>
#include <cstdint>
#include <cstddef>

typedef __attribute__((ext_vector_type(8))) short short8;
typedef __attribute__((ext_vector_type(4))) float f32x4;

#define NB 512
#define DD 4096

__device__ __forceinline__ unsigned short f2bf(float f) {
    unsigned u = __float_as_uint(f);
    u += 0x7fffu + ((u >> 16) & 1u);
    return (unsigned short)(u >> 16);
}
__device__ __forceinline__ unsigned pack2bf(float a, float b) {
    return (unsigned)f2bf(a) | ((unsigned)f2bf(b) << 16);
}

__device__ __forceinline__ void gload_lds16(const void* g, void* l) {
    __builtin_amdgcn_global_load_lds((const __attribute__((address_space(1))) void*)g,
                                     (__attribute__((address_space(3))) void*)l, 16, 0, 0);
}

// ---------------- x -> bf16 ----------------
__global__ __launch_bounds__(256) void cvt_bf16_kernel(const float* __restrict__ src,
                                                       unsigned short* __restrict__ dst,
                                                       int n8) {
    int i = blockIdx.x * 256 + threadIdx.x;
    if (i >= n8) return;
    const float4* s = (const float4*)src + (size_t)i * 2;
    float4 a = s[0], b = s[1];
    uint4 r;
    r.x = pack2bf(a.x, a.y);
    r.y = pack2bf(a.z, a.w);
    r.z = pack2bf(b.x, b.y);
    r.w = pack2bf(b.z, b.w);
    ((uint4*)dst)[i] = r;
}

// ---------------- q,k,v = x @ W^T (bf16 MFMA, f32 out) ----------------
// C[m][n] = sum_d A[m][d] * W[n][d]; A bf16 (pre-cvt), W f32 (reg-staged -> bf16 LDS)
__global__ __launch_bounds__(256, 2) void gemm_qkv_kernel(
    const unsigned short* __restrict__ xb,
    const float* __restrict__ w0, const float* __restrict__ w1, const float* __restrict__ w2,
    float* __restrict__ qkv)
{
    const int nt = blockIdx.x;   // 0..31  N tile
    const int mt = blockIdx.y;   // 0..3   M tile
    const int mz = blockIdx.z;   // 0..2   which matrix
    const float* W = (mz == 0) ? w0 : ((mz == 1) ? w1 : w2);
    float* C = qkv + (size_t)mz * ((size_t)NB * DD);

    __shared__ unsigned short As[2][128 * 64];
    __shared__ unsigned short Bs[2][128 * 64];

    const int t = threadIdx.x;
    const int l = t & 63;
    const int wv = t >> 6;
    const int wr = wv >> 1, wc = wv & 1;

    const unsigned short* Abase = xb + (size_t)(mt * 128) * DD;
    const float* Wbase = W + (size_t)(nt * 128) * DD;

    f32x4 acc[4][4];
    #pragma unroll
    for (int i = 0; i < 4; ++i)
        #pragma unroll
        for (int j = 0; j < 4; ++j)
            acc[i][j] = (f32x4){0.f, 0.f, 0.f, 0.f};

    float4 breg[8];

    // prologue: stage K-tile 0 into buffer 0
    #pragma unroll
    for (int p = 0; p < 8; ++p) {
        int qq = p * 256 + t;
        int row = qq >> 4, c4 = qq & 15;
        breg[p] = *(const float4*)(Wbase + (size_t)row * DD + c4 * 4);
    }
    #pragma unroll
    for (int i = 0; i < 4; ++i) {
        int e = i * 256 + t;
        int r = e >> 3;
        int c = ((e & 7) * 8) ^ ((r & 7) * 8);   // pre-swizzled source column
        gload_lds16(Abase + (size_t)r * DD + c,
                    (char*)(&As[0][0]) + i * 4096 + wv * 1024);
    }
    #pragma unroll
    for (int p = 0; p < 8; ++p) {
        int qq = p * 256 + t;
        int row = qq >> 4, c4 = qq & 15;
        unsigned short* dst = &Bs[0][row * 64 + ((c4 * 4) ^ ((row & 7) * 8))];
        uint2 pk;
        pk.x = pack2bf(breg[p].x, breg[p].y);
        pk.y = pack2bf(breg[p].z, breg[p].w);
        *(uint2*)dst = pk;
    }
    __syncthreads();

    for (int kt = 0; kt < 64; ++kt) {
        const int cur = kt & 1, nxt = cur ^ 1;
        const int kn = (kt + 1) * 64;
        if (kt < 63) {
            #pragma unroll
            for (int p = 0; p < 8; ++p) {
                int qq = p * 256 + t;
                int row = qq >> 4, c4 = qq & 15;
                breg[p] = *(const float4*)(Wbase + (size_t)row * DD + kn + c4 * 4);
            }
            #pragma unroll
            for (int i = 0; i < 4; ++i) {
                int e = i * 256 + t;
                int r = e >> 3;
                int c = ((e & 7) * 8) ^ ((r & 7) * 8);
                gload_lds16(Abase + (size_t)r * DD + kn + c,
                            (char*)(&As[nxt][0]) + i * 4096 + wv * 1024);
            }
        }
        // compute on current buffer
        #pragma unroll
        for (int ks = 0; ks < 2; ++ks) {
            short8 af[4], bf[4];
            #pragma unroll
            for (int fi = 0; fi < 4; ++fi) {
                int row = wr * 64 + fi * 16 + (l & 15);
                int off = row * 64 + ((ks * 32 + (l >> 4) * 8) ^ ((row & 7) * 8));
                af[fi] = *(const short8*)(&As[cur][off]);
            }
            #pragma unroll
            for (int fj = 0; fj < 4; ++fj) {
                int row = wc * 64 + fj * 16 + (l & 15);
                int off = row * 64 + ((ks * 32 + (l >> 4) * 8) ^ ((row & 7) * 8));
                bf[fj] = *(const short8*)(&Bs[cur][off]);
            }
            #pragma unroll
            for (int fi = 0; fi < 4; ++fi)
                #pragma unroll
                for (int fj = 0; fj < 4; ++fj)
                    acc[fi][fj] = __builtin_amdgcn_mfma_f32_16x16x32_bf16(af[fi], bf[fj], acc[fi][fj], 0, 0, 0);
        }
        // late write of next B tile (hides W load latency under MFMA)
        if (kt < 63) {
            #pragma unroll
            for (int p = 0; p < 8; ++p) {
                int qq = p * 256 + t;
                int row = qq >> 4, c4 = qq & 15;
                unsigned short* dst = &Bs[nxt][row * 64 + ((c4 * 4) ^ ((row & 7) * 8))];
                uint2 pk;
                pk.x = pack2bf(breg[p].x, breg[p].y);
                pk.y = pack2bf(breg[p].z, breg[p].w);
                *(uint2*)dst = pk;
            }
        }
        __syncthreads();
    }

    #pragma unroll
    for (int fi = 0; fi < 4; ++fi) {
        int rbase = mt * 128 + wr * 64 + fi * 16 + (l >> 4) * 4;
        #pragma unroll
        for (int fj = 0; fj < 4; ++fj) {
            int col = nt * 128 + wc * 64 + fj * 16 + (l & 15);
            #pragma unroll
            for (int r = 0; r < 4; ++r)
                C[(size_t)(rbase + r) * DD + col] = acc[fi][fj][r];
        }
    }
}

// ---------------- per-batch attention (f32 VALU) ----------------
__global__ __launch_bounds__(256) void attn_kernel(
    const float* __restrict__ qkv,
    const float* __restrict__ x,
    const float* __restrict__ imap,
    float* __restrict__ dout)
{
    const int b = blockIdx.x;
    const int t = threadIdx.x;
    const int l = t & 63;
    const int wv = t >> 6;

    __shared__ float sq[64 * 68];
    __shared__ float sk[64 * 68];   // reused as P with stride 65
    __shared__ float sv[64 * 68];

    const float* qb = qkv + (size_t)b * DD;
    const float* kb = qkv + (size_t)NB * DD + (size_t)b * DD;
    const float* vb = qkv + 2 * (size_t)NB * DD + (size_t)b * DD;

    #pragma unroll
    for (int i = 0; i < 4; ++i) {
        int f4 = i * 256 + t;
        int r = f4 >> 4, c = (f4 & 15) * 4;
        *(float4*)(&sq[r * 68 + c]) = *(const float4*)(qb + (size_t)f4 * 4);
        *(float4*)(&sk[r * 68 + c]) = *(const float4*)(kb + (size_t)f4 * 4);
        *(float4*)(&sv[r * 68 + c]) = *(const float4*)(vb + (size_t)f4 * 4);
    }
    __syncthreads();

    // S[h][g] = (q_h . k_g)/8 * imap[h][g]; thread: rows h=i*4+wv, col g=l
    float accs[16];
    #pragma unroll
    for (int i = 0; i < 16; ++i) accs[i] = 0.f;
    #pragma unroll 4
    for (int f4 = 0; f4 < 16; ++f4) {
        float4 kvv = *(const float4*)(&sk[l * 68 + f4 * 4]);
        #pragma unroll
        for (int i = 0; i < 16; ++i) {
            int h = i * 4 + wv;
            float4 qv = *(const float4*)(&sq[h * 68 + f4 * 4]);
            accs[i] = fmaf(qv.x, kvv.x, fmaf(qv.y, kvv.y, fmaf(qv.z, kvv.z, fmaf(qv.w, kvv.w, accs[i]))));
        }
    }
    __syncthreads();   // all sk reads complete before overwrite as P
    #pragma unroll
    for (int i = 0; i < 16; ++i) {
        int h = i * 4 + wv;
        float m = imap[(size_t)b * DD + h * 64 + l];
        sk[h * 65 + l] = accs[i] * 0.125f * m;
    }
    __syncthreads();

    // softmax over g: thread -> row h=t>>2, cols j*16..j*16+15
    {
        int h = t >> 2, j = t & 3;
        float e[16];
        float mx = -3.0e38f;
        #pragma unroll
        for (int q2 = 0; q2 < 16; ++q2) {
            e[q2] = sk[h * 65 + j * 16 + q2];
            mx = fmaxf(mx, e[q2]);
        }
        mx = fmaxf(mx, __shfl_xor(mx, 1));
        mx = fmaxf(mx, __shfl_xor(mx, 2));
        float s = 0.f;
        #pragma unroll
        for (int q2 = 0; q2 < 16; ++q2) { e[q2] = __expf(e[q2] - mx); s += e[q2]; }
        s += __shfl_xor(s, 1);
        s += __shfl_xor(s, 2);
        float invs = 1.0f / s;
        float* aw = dout + (size_t)NB * DD + (size_t)b * DD + h * 64 + j * 16;
        #pragma unroll
        for (int q2 = 0; q2 < 16; q2 += 4) {
            float4 w4 = {e[q2] * invs, e[q2 + 1] * invs, e[q2 + 2] * invs, e[q2 + 3] * invs};
            *(float4*)(aw + q2) = w4;
            sk[h * 65 + j * 16 + q2 + 0] = w4.x;
            sk[h * 65 + j * 16 + q2 + 1] = w4.y;
            sk[h * 65 + j * 16 + q2 + 2] = w4.z;
            sk[h * 65 + j * 16 + q2 + 3] = w4.w;
        }
    }
    __syncthreads();

    // weighted[h][f] = sum_g P[h][g] v[g][f]; lane row h=l, f block wv*16
    float pacc[16];
    #pragma unroll
    for (int i = 0; i < 16; ++i) pacc[i] = 0.f;
    #pragma unroll 4
    for (int g = 0; g < 64; ++g) {
        float p = sk[l * 65 + g];
        const float4* vr = (const float4*)(&sv[g * 68 + wv * 16]);
        float4 v0 = vr[0], v1 = vr[1], v2 = vr[2], v3 = vr[3];
        pacc[0]  = fmaf(p, v0.x, pacc[0]);
        pacc[1]  = fmaf(p, v0.y, pacc[1]);
        pacc[2]  = fmaf(p, v0.z, pacc[2]);
        pacc[3]  = fmaf(p, v0.w, pacc[3]);
        pacc[4]  = fmaf(p, v1.x, pacc[4]);
        pacc[5]  = fmaf(p, v1.y, pacc[5]);
        pacc[6]  = fmaf(p, v1.z, pacc[6]);
        pacc[7]  = fmaf(p, v1.w, pacc[7]);
        pacc[8]  = fmaf(p, v2.x, pacc[8]);
        pacc[9]  = fmaf(p, v2.y, pacc[9]);
        pacc[10] = fmaf(p, v2.z, pacc[10]);
        pacc[11] = fmaf(p, v2.w, pacc[11]);
        pacc[12] = fmaf(p, v3.x, pacc[12]);
        pacc[13] = fmaf(p, v3.y, pacc[13]);
        pacc[14] = fmaf(p, v3.z, pacc[14]);
        pacc[15] = fmaf(p, v3.w, pacc[15]);
    }
    // out[b, xl=f, yl=h] = x * weighted[h][f]
    const size_t ob = (size_t)b * DD + (size_t)(wv * 16) * 64 + l;
    #pragma unroll
    for (int ii = 0; ii < 16; ++ii) {
        size_t o = ob + (size_t)ii * 64;
        dout[o] = x[o] * pacc[ii];
    }
}

extern "C" void kernel_launch(void* const* d_in, const int* in_sizes, int n_in,
                              void* d_out, int out_size, void* d_ws, size_t ws_size,
                              hipStream_t stream) {
    const float* x  = (const float*)d_in[0];
    const float* im = (const float*)d_in[1];
    const float* Wq = (const float*)d_in[2];
    const float* Wk = (const float*)d_in[3];
    const float* Wv = (const float*)d_in[4];
    float* out = (float*)d_out;

    unsigned short* xb = (unsigned short*)d_ws;                       // 4 MiB
    float* qkv = (float*)((char*)d_ws + (size_t)NB * DD * 2);         // 24 MiB (q,k,v f32)

    cvt_bf16_kernel<<<dim3((NB * DD / 8 + 255) / 256), dim3(256), 0, stream>>>(x, xb, NB * DD / 8);

    dim3 gg(32, 4, 3);
    gemm_qkv_kernel<<<gg, dim3(256), 0, stream>>>(xb, Wq, Wk, Wv, qkv);

    attn_kernel<<<dim3(NB), dim3(256), 0, stream>>>(qkv, x, im, out);
}